// Round 6
// baseline (738.487 us; speedup 1.0000x reference)
//
#include <hip/hip_runtime.h>
#include <hip/hip_bf16.h>

typedef unsigned int u32;
typedef unsigned char u8;

#define B_ 256
#define T_ 512
#define E_ 100
#define H_ 64
#define K_ 17
#define V_ 8000

// ---- ws layout (bytes) ----
#define WS_G     0            // 2 * 8000 * 256 * 4 = 16,384,000
#define WS_H     16384000     // 2 * 256 * 512 * 64 * 4 = 67,108,864
#define WS_EMIT  83492864     // 131072 * 17 * 4 = 8,912,896
#define WS_BP    92405760     // 256 * 512 * 32 = 4,194,304
#define WS_LAST  96600064     // 256 * 4

// Pin a value into a VGPR: opaque to the compiler -> cannot rematerialize the
// producing load, cannot sink it into a loop. Zero instructions emitted.
#define PIN(x) asm volatile("" : "+v"(x))

// quad_perm DPP: xor1 = [1,0,3,2] = 0xB1, xor2 = [2,3,0,1] = 0x4E
__device__ __forceinline__ float qp_xor1(float v) {
  int r = __builtin_amdgcn_update_dpp(0, __builtin_bit_cast(int, v), 0xB1, 0xF, 0xF, true);
  return __builtin_bit_cast(float, r);
}
__device__ __forceinline__ float qp_xor2(float v) {
  int r = __builtin_amdgcn_update_dpp(0, __builtin_bit_cast(int, v), 0x4E, 0xF, 0xF, true);
  return __builtin_bit_cast(float, r);
}

// ============ K1: G[v][u*4+g] = emb[v] @ Wih[g*64+u].T + bih + bhh ============
__global__ __launch_bounds__(256) void k1_build_G(
    const float* __restrict__ emb,
    const float* __restrict__ Wih_f,
    const float* __restrict__ bih_f,
    const float* __restrict__ bhh_f,
    const float* __restrict__ Wih_b,
    const float* __restrict__ bih_b,
    const float* __restrict__ bhh_b,
    float* __restrict__ G)
{
  __shared__ float xl[32 * E_];
  int v0 = blockIdx.x * 32;
  int dir = blockIdx.y;
  int tid = threadIdx.x;
  const float* Wih = dir ? Wih_b : Wih_f;
  const float* bih = dir ? bih_b : bih_f;
  const float* bhh = dir ? bhh_b : bhh_f;

  for (int i = tid; i < 32 * E_; i += 256) xl[i] = emb[v0 * E_ + i];

  int u = tid >> 2, g = tid & 3;
  int row = (g << 6) + u;
  float Af[100];
  {
    const float4* wp = reinterpret_cast<const float4*>(Wih + row * E_); // 400B rows, 16B aligned
#pragma unroll
    for (int q = 0; q < 25; ++q) {
      float4 v = wp[q];
      Af[q * 4 + 0] = v.x; Af[q * 4 + 1] = v.y;
      Af[q * 4 + 2] = v.z; Af[q * 4 + 3] = v.w;
    }
  }
#pragma unroll
  for (int q = 0; q < 100; ++q) PIN(Af[q]);   // keep weights register-resident
  float bias = __fadd_rn(bih[row], bhh[row]);
  __syncthreads();

  float* Gd = G + (size_t)dir * V_ * 256;
  for (int vi = 0; vi < 32; ++vi) {
    const float* xp = &xl[vi * E_];   // vi*400B, 16B aligned
    float a0 = bias, a1 = 0.f, a2 = 0.f, a3 = 0.f;
#pragma unroll
    for (int q = 0; q < 25; ++q) {
      float4 x4 = *reinterpret_cast<const float4*>(&xp[4 * q]);
      a0 = fmaf(Af[q * 4 + 0], x4.x, a0);
      a1 = fmaf(Af[q * 4 + 1], x4.y, a1);
      a2 = fmaf(Af[q * 4 + 2], x4.z, a2);
      a3 = fmaf(Af[q * 4 + 3], x4.w, a3);
    }
    Gd[(v0 + vi) * 256 + tid] = (a0 + a1) + (a2 + a3);
  }
}

// ============ K2: BiLSTM recurrence. 1 block = (b, dir), 4 waves ============
// lane l: unit u = w*16 + (l>>2), K-quarter kq = l&3. All 4 gates per lane.
// Whh slice PINNED in 64 VGPRs (round-5 post-mortem: compiler was re-loading
// it from L1 every step; VGPR_Count 56 proved it was never resident).
// h broadcast: 4 ds_read_b128/wave; combine via DPP quad_perm (VALU pipe).
// Raw s_barrier (lgkmcnt-only drain) keeps G prefetch loads in flight.
__global__ __launch_bounds__(256, 2) void k2_lstm(
    const int* __restrict__ data,
    const float* __restrict__ G,
    const float* __restrict__ Whh_f,
    const float* __restrict__ Whh_b,
    float* __restrict__ hout)
{
  __shared__ __align__(16) float hls[2][64];
  int bid = blockIdx.x;
  int b = bid & 255;
  int dir = bid >> 8;
  int tid = threadIdx.x;
  int w = tid >> 6, l = tid & 63;
  int ul = l >> 2;           // 0..15
  int kq = l & 3;            // K-quarter
  int u = (w << 4) + ul;     // 0..63
  const float* Whh = dir ? Whh_b : Whh_f;

  // Wf[g*16 + kk]: gate g's row, K-slice [kq*16, kq*16+16)
  float Wf[64];
#pragma unroll
  for (int g = 0; g < 4; ++g) {
    const float4* wp = reinterpret_cast<const float4*>(Whh + ((g << 6) + u) * 64 + (kq << 4));
#pragma unroll
    for (int q = 0; q < 4; ++q) {
      float4 v = wp[q];
      Wf[g * 16 + q * 4 + 0] = v.x;
      Wf[g * 16 + q * 4 + 1] = v.y;
      Wf[g * 16 + q * 4 + 2] = v.z;
      Wf[g * 16 + q * 4 + 3] = v.w;
    }
  }
#pragma unroll
  for (int q = 0; q < 64; ++q) PIN(Wf[q]);    // register-resident across T-loop

  if (tid < 64) hls[0][tid] = 0.0f;
  float c = 0.0f;
  const int* tokp = data + b * T_;
  const float* Gd = G + (size_t)dir * V_ * 256;
  float* hob = hout + ((size_t)(dir * B_ + b)) * T_ * H_;
  const float L2E = 1.4426950408889634f;

  // 3-ahead G prefetch ring
  float4 gq0 = *reinterpret_cast<const float4*>(&Gd[(size_t)tokp[dir ? (T_ - 1) : 0] * 256 + (u << 2)]);
  float4 gq1 = *reinterpret_cast<const float4*>(&Gd[(size_t)tokp[dir ? (T_ - 2) : 1] * 256 + (u << 2)]);
  float4 gq2 = *reinterpret_cast<const float4*>(&Gd[(size_t)tokp[dir ? (T_ - 3) : 2] * 256 + (u << 2)]);
  __syncthreads();

  int cur = 0;
  for (int s = 0; s < T_; ++s) {
    int tt = dir ? (T_ - 1 - s) : s;
    float4 gq3 = make_float4(0.f, 0.f, 0.f, 0.f);
    if (s < T_ - 3) {
      int ttn = dir ? (T_ - 4 - s) : (s + 3);
      gq3 = *reinterpret_cast<const float4*>(&Gd[(size_t)tokp[ttn] * 256 + (u << 2)]);
    }
    const float* hq = hls[cur] + (kq << 4);
    float4 h4[4];
#pragma unroll
    for (int q = 0; q < 4; ++q) h4[q] = *reinterpret_cast<const float4*>(&hq[q * 4]);
    float acc[4];
#pragma unroll
    for (int g = 0; g < 4; ++g) {
      float b0 = 0.f, b1 = 0.f, b2 = 0.f, b3 = 0.f;
#pragma unroll
      for (int q = 0; q < 4; ++q) {
        b0 = fmaf(Wf[g * 16 + q * 4 + 0], h4[q].x, b0);
        b1 = fmaf(Wf[g * 16 + q * 4 + 1], h4[q].y, b1);
        b2 = fmaf(Wf[g * 16 + q * 4 + 2], h4[q].z, b2);
        b3 = fmaf(Wf[g * 16 + q * 4 + 3], h4[q].w, b3);
      }
      acc[g] = (b0 + b1) + (b2 + b3);
    }
    // quad butterfly (DPP, no DS ops): every lane gets full 64-sum per gate
    float t0 = acc[0] + qp_xor1(acc[0]); float f0 = t0 + qp_xor2(t0);
    float t1 = acc[1] + qp_xor1(acc[1]); float f1 = t1 + qp_xor2(t1);
    float t2 = acc[2] + qp_xor1(acc[2]); float f2 = t2 + qp_xor2(t2);
    float t3 = acc[3] + qp_xor1(acc[3]); float f3 = t3 + qp_xor2(t3);
    float xi = f0 + gq0.x;
    float xf = f1 + gq0.y;
    float xg = f2 + gq0.z;
    float xo = f3 + gq0.w;
    // same activation formulas as rounds 4/5 (verified absmax 0.0)
    float si = __builtin_amdgcn_rcpf(1.0f + __builtin_amdgcn_exp2f(xi * (-L2E)));
    float sf = __builtin_amdgcn_rcpf(1.0f + __builtin_amdgcn_exp2f(xf * (-L2E)));
    float tg = fmaf(2.0f, __builtin_amdgcn_rcpf(1.0f + __builtin_amdgcn_exp2f(xg * (-2.0f * L2E))), -1.0f);
    float so = __builtin_amdgcn_rcpf(1.0f + __builtin_amdgcn_exp2f(xo * (-L2E)));
    c = __fadd_rn(__fmul_rn(sf, c), __fmul_rn(si, tg));
    float tc = fmaf(2.0f, __builtin_amdgcn_rcpf(1.0f + __builtin_amdgcn_exp2f(c * (-2.0f * L2E))), -1.0f);
    float hn = __fmul_rn(so, tc);
    if (kq == 0) {
      hls[cur ^ 1][u] = hn;
      hob[tt * H_ + u] = hn;
    }
    // raw barrier: drain LDS only; global prefetch loads stay in flight
    asm volatile("s_waitcnt lgkmcnt(0)\n\ts_barrier" ::: "memory");
    cur ^= 1;
    gq0 = gq1; gq1 = gq2; gq2 = gq3;
  }
}

// ============ K3: emissions = [hf|hb] @ W_out.T + b_out ============
__global__ __launch_bounds__(256) void k3_emit(
    const float* __restrict__ hbuf,
    const float* __restrict__ W_out,
    const float* __restrict__ b_out,
    float* __restrict__ emit)
{
  __shared__ float hl[64][132];
  __shared__ float Wl[17][132];
  int tid = threadIdx.x;
  int p0 = blockIdx.x * 64;  // flat position base (b*T + t), 64 consecutive t
  const float* hf = hbuf;
  const float* hb = hbuf + (size_t)B_ * T_ * H_;
#pragma unroll
  for (int i = 0; i < 4; ++i) {
    int idx = tid + i * 256;       // float4 index among 1024
    int pos = idx >> 4, e4 = idx & 15;
    float4 v = reinterpret_cast<const float4*>(hf + (size_t)p0 * 64)[idx];
    *reinterpret_cast<float4*>(&hl[pos][e4 * 4]) = v;
    float4 v2 = reinterpret_cast<const float4*>(hb + (size_t)p0 * 64)[idx];
    *reinterpret_cast<float4*>(&hl[pos][64 + e4 * 4]) = v2;
  }
  for (int i = tid; i < 17 * 128; i += 256) {
    int k = i >> 7, e = i & 127;
    Wl[k][e] = W_out[i];
  }
  __syncthreads();

  int pos = tid >> 2, ks = tid & 3;
  float acc[5] = {0.f, 0.f, 0.f, 0.f, 0.f};
#pragma unroll
  for (int e4 = 0; e4 < 32; ++e4) {
    float4 x4 = *reinterpret_cast<const float4*>(&hl[pos][e4 * 4]);
#pragma unroll
    for (int kk = 0; kk < 5; ++kk) {
      int k = ks + kk * 4;
      if (k < K_) {
        float4 w4 = *reinterpret_cast<const float4*>(&Wl[k][e4 * 4]);
        acc[kk] = fmaf(x4.x, w4.x, acc[kk]);
        acc[kk] = fmaf(x4.y, w4.y, acc[kk]);
        acc[kk] = fmaf(x4.z, w4.z, acc[kk]);
        acc[kk] = fmaf(x4.w, w4.w, acc[kk]);
      }
    }
  }
#pragma unroll
  for (int kk = 0; kk < 5; ++kk) {
    int k = ks + kk * 4;
    if (k < K_)
      emit[(size_t)(p0 + pos) * K_ + k] = __fadd_rn(acc[kk], b_out[k]);
  }
}

// ============ K4: Viterbi forward. 1 wave per b; lane = (half ic, tag j) ============
#define AMAX(vA, iA, vB, iB) { bool tk_ = (vB) > (vA); if (tk_) { vA = (vB); iA = (iB); } }

__global__ __launch_bounds__(64) void k4_viterbi(
    const float* __restrict__ emit,
    const float* __restrict__ trans,
    const float* __restrict__ start_trans,
    const float* __restrict__ end_trans,
    u8* __restrict__ bp,
    int* __restrict__ last,
    float* __restrict__ out)
{
  int b = blockIdx.x;
  int l = threadIdx.x;
  int ic = l >> 5;
  int hbase = l & 32;
  int j = l & 31;
  int jc = (j < K_) ? j : 0;
  int i0 = ic ? 9 : 0;
  int cnt = ic ? 8 : 9;
  float tr[9];
#pragma unroll
  for (int q = 0; q < 9; ++q)
    tr[q] = (q < cnt) ? trans[(i0 + q) * K_ + jc] : -__builtin_inff();
#pragma unroll
  for (int q = 0; q < 9; ++q) PIN(tr[q]);
  const float* eb = emit + (size_t)b * T_ * K_;
  float endt = end_trans[jc];
  float s = __fadd_rn(start_trans[jc], eb[jc]);
  u8* bpb = bp + (size_t)b * T_ * 32;
  // 4-deep emission prefetch ring
  float er0 = eb[1 * K_ + jc];
  float er1 = eb[2 * K_ + jc];
  float er2 = eb[3 * K_ + jc];
  float er3 = eb[4 * K_ + jc];

  for (int t = 1; t < T_; ++t) {
    float ej = er0;
    er0 = er1; er1 = er2; er2 = er3;
    if (t + 4 < T_) er3 = eb[(size_t)(t + 4) * K_ + jc];
    float sv[9];
#pragma unroll
    for (int q = 0; q < 9; ++q) sv[q] = __shfl(s, hbase + i0 + q, 64);
    // np rounding order: cand = (score_i + trans_ij) + emit_j
    float cd[9];
#pragma unroll
    for (int q = 0; q < 9; ++q) cd[q] = __fadd_rn(__fadd_rn(sv[q], tr[q]), ej);
    // tree argmax; strict > with left-priority == np first-index tie rule
    float v01 = cd[0]; int x01 = i0;     AMAX(v01, x01, cd[1], i0 + 1);
    float v23 = cd[2]; int x23 = i0 + 2; AMAX(v23, x23, cd[3], i0 + 3);
    float v45 = cd[4]; int x45 = i0 + 4; AMAX(v45, x45, cd[5], i0 + 5);
    float v67 = cd[6]; int x67 = i0 + 6; AMAX(v67, x67, cd[7], i0 + 7);
    AMAX(v01, x01, v23, x23);
    AMAX(v45, x45, v67, x67);
    AMAX(v01, x01, v45, x45);
    AMAX(v01, x01, cd[8], i0 + 8);
    float m = v01; int idx = x01;
    float m2 = __shfl_xor(m, 32, 64);
    int idx2 = __shfl_xor(idx, 32, 64);
    bool take = (m2 > m) || ((m2 == m) && (idx2 < idx));
    if (take) { m = m2; idx = idx2; }
    s = m;
    if (ic == 0 && j < K_) bpb[(size_t)(t - 1) * 32 + j] = (u8)idx;
  }
  float fin = __fadd_rn(s, endt);
  float bm = __shfl(fin, hbase, 64);
  int bi = 0;
#pragma unroll
  for (int jj = 1; jj < K_; ++jj) {
    float v = __shfl(fin, hbase + jj, 64);
    if (v > bm) { bm = v; bi = jj; }
  }
  if (l == 0) {
    out[b] = bm;
    last[b] = bi;
    out[256 + (size_t)b * T_ + (T_ - 1)] = (float)bi;
  }
}

// ============ K5: backtrace — 8-deep double-buffered prefetch ============
__global__ __launch_bounds__(64) void k5_backtrace(
    const u8* __restrict__ bp,
    const int* __restrict__ last,
    float* __restrict__ out)
{
  int b = blockIdx.x * 64 + threadIdx.x;
  const u8* base = bp + (size_t)b * T_ * 32;
  int tag = last[b];
  float* ob = out + 256 + (size_t)b * T_;
  uint4 A0[8], A1[8];
  u32 B0[8], B1[8];
#pragma unroll
  for (int q = 0; q < 8; ++q) {
    const u8* p = base + (size_t)(510 - q) * 32;
    A0[q] = *reinterpret_cast<const uint4*>(p);
    B0[q] = *reinterpret_cast<const u32*>(p + 16);
  }
  int t0 = 510;
  for (int pair = 0; pair < 32; ++pair) {
#pragma unroll
    for (int q = 0; q < 8; ++q) {
      int tn = t0 - 8 - q;
      if (tn >= 0) {
        const u8* p = base + (size_t)tn * 32;
        A1[q] = *reinterpret_cast<const uint4*>(p);
        B1[q] = *reinterpret_cast<const u32*>(p + 16);
      }
    }
#pragma unroll
    for (int q = 0; q < 8; ++q) {
      int t = t0 - q;
      if (t >= 0) {
        uint4 Av = A0[q]; u32 Bw = B0[q];
        u32 dw = (tag < 8) ? ((tag < 4) ? Av.x : Av.y) : ((tag < 12) ? Av.z : Av.w);
        dw = (tag < 16) ? dw : Bw;
        tag = (int)((dw >> ((tag & 3) * 8)) & 0xffu);
        ob[t] = (float)tag;
      }
    }
#pragma unroll
    for (int q = 0; q < 8; ++q) {
      int tn = t0 - 16 - q;
      if (tn >= 0) {
        const u8* p = base + (size_t)tn * 32;
        A0[q] = *reinterpret_cast<const uint4*>(p);
        B0[q] = *reinterpret_cast<const u32*>(p + 16);
      }
    }
#pragma unroll
    for (int q = 0; q < 8; ++q) {
      int t = t0 - 8 - q;
      if (t >= 0) {
        uint4 Av = A1[q]; u32 Bw = B1[q];
        u32 dw = (tag < 8) ? ((tag < 4) ? Av.x : Av.y) : ((tag < 12) ? Av.z : Av.w);
        dw = (tag < 16) ? dw : Bw;
        tag = (int)((dw >> ((tag & 3) * 8)) & 0xffu);
        ob[t] = (float)tag;
      }
    }
    t0 -= 16;
  }
}

extern "C" void kernel_launch(void* const* d_in, const int* in_sizes, int n_in,
                              void* d_out, int out_size, void* d_ws, size_t ws_size,
                              hipStream_t stream) {
  const int*   data  = (const int*)d_in[0];
  const float* emb   = (const float*)d_in[2];
  const float* Wih_f = (const float*)d_in[3];
  const float* Whh_f = (const float*)d_in[4];
  const float* bih_f = (const float*)d_in[5];
  const float* bhh_f = (const float*)d_in[6];
  const float* Wih_b = (const float*)d_in[7];
  const float* Whh_b = (const float*)d_in[8];
  const float* bih_b = (const float*)d_in[9];
  const float* bhh_b = (const float*)d_in[10];
  const float* W_out = (const float*)d_in[11];
  const float* b_out = (const float*)d_in[12];
  const float* trans = (const float*)d_in[13];
  const float* start_trans = (const float*)d_in[14];
  const float* end_trans   = (const float*)d_in[15];

  char* ws = (char*)d_ws;
  float* G    = (float*)(ws + WS_G);
  float* hbuf = (float*)(ws + WS_H);
  float* emit = (float*)(ws + WS_EMIT);
  u8*    bp   = (u8*)(ws + WS_BP);
  int*   lastp = (int*)(ws + WS_LAST);
  float* out = (float*)d_out;

  k1_build_G<<<dim3(250, 2), 256, 0, stream>>>(emb, Wih_f, bih_f, bhh_f,
                                               Wih_b, bih_b, bhh_b, G);
  k2_lstm<<<512, 256, 0, stream>>>(data, G, Whh_f, Whh_b, hbuf);
  k3_emit<<<2048, 256, 0, stream>>>(hbuf, W_out, b_out, emit);
  k4_viterbi<<<256, 64, 0, stream>>>(emit, trans, start_trans, end_trans,
                                     bp, lastp, out);
  k5_backtrace<<<4, 64, 0, stream>>>(bp, lastp, out);
}

// Round 7
// 685.652 us; speedup vs baseline: 1.0771x; 1.0771x over previous
//
#include <hip/hip_runtime.h>
#include <hip/hip_bf16.h>

typedef unsigned int u32;
typedef unsigned char u8;

#define B_ 256
#define T_ 512
#define E_ 100
#define H_ 64
#define K_ 17
#define V_ 8000

// ---- ws layout (bytes) ----
#define WS_G     0            // 2 * 8000 * 256 * 4 = 16,384,000
#define WS_H     16384000     // 2 * 256 * 512 * 64 * 4 = 67,108,864
#define WS_EMIT  83492864     // 131072 * 17 * 4 = 8,912,896
#define WS_BP    92405760     // 256 * 512 * 32 = 4,194,304
#define WS_LAST  96600064     // 256 * 4

// SROA-safe register pinning: STATIC indices only (round-6 post-mortem:
// PIN inside a pragma-unroll loop is runtime-indexed at SROA time -> the
// whole array went to scratch, VGPR stayed 56, dur regressed 331->407).
#define PIN16(A,i) asm volatile("" : \
  "+v"((A)[(i)+0]), "+v"((A)[(i)+1]), "+v"((A)[(i)+2]), "+v"((A)[(i)+3]), \
  "+v"((A)[(i)+4]), "+v"((A)[(i)+5]), "+v"((A)[(i)+6]), "+v"((A)[(i)+7]), \
  "+v"((A)[(i)+8]), "+v"((A)[(i)+9]), "+v"((A)[(i)+10]),"+v"((A)[(i)+11]), \
  "+v"((A)[(i)+12]),"+v"((A)[(i)+13]),"+v"((A)[(i)+14]),"+v"((A)[(i)+15]))
#define PIN4(A,i) asm volatile("" : \
  "+v"((A)[(i)+0]), "+v"((A)[(i)+1]), "+v"((A)[(i)+2]), "+v"((A)[(i)+3]))

// quad_perm DPP: xor1 = [1,0,3,2] = 0xB1, xor2 = [2,3,0,1] = 0x4E
__device__ __forceinline__ float qp_xor1(float v) {
  int r = __builtin_amdgcn_update_dpp(0, __builtin_bit_cast(int, v), 0xB1, 0xF, 0xF, true);
  return __builtin_bit_cast(float, r);
}
__device__ __forceinline__ float qp_xor2(float v) {
  int r = __builtin_amdgcn_update_dpp(0, __builtin_bit_cast(int, v), 0x4E, 0xF, 0xF, true);
  return __builtin_bit_cast(float, r);
}

// ============ K1: G[v][u*4+g] = emb[v] @ Wih[g*64+u].T + bih + bhh ============
__global__ __launch_bounds__(256, 2) void k1_build_G(
    const float* __restrict__ emb,
    const float* __restrict__ Wih_f,
    const float* __restrict__ bih_f,
    const float* __restrict__ bhh_f,
    const float* __restrict__ Wih_b,
    const float* __restrict__ bih_b,
    const float* __restrict__ bhh_b,
    float* __restrict__ G)
{
  __shared__ float xl[32 * E_];
  int v0 = blockIdx.x * 32;
  int dir = blockIdx.y;
  int tid = threadIdx.x;
  const float* Wih = dir ? Wih_b : Wih_f;
  const float* bih = dir ? bih_b : bih_f;
  const float* bhh = dir ? bhh_b : bhh_f;

  for (int i = tid; i < 32 * E_; i += 256) xl[i] = emb[v0 * E_ + i];

  int u = tid >> 2, g = tid & 3;
  int row = (g << 6) + u;
  float Af[100];
  {
    const float4* wp = reinterpret_cast<const float4*>(Wih + row * E_); // 400B rows, 16B aligned
#pragma unroll
    for (int q = 0; q < 25; ++q) {
      float4 v = wp[q];
      Af[q * 4 + 0] = v.x; Af[q * 4 + 1] = v.y;
      Af[q * 4 + 2] = v.z; Af[q * 4 + 3] = v.w;
    }
  }
  PIN16(Af, 0);  PIN16(Af, 16); PIN16(Af, 32);
  PIN16(Af, 48); PIN16(Af, 64); PIN16(Af, 80);
  PIN4(Af, 96);
  float bias = __fadd_rn(bih[row], bhh[row]);
  __syncthreads();

  float* Gd = G + (size_t)dir * V_ * 256;
  for (int vi = 0; vi < 32; ++vi) {
    const float* xp = &xl[vi * E_];   // vi*400B, 16B aligned
    float a0 = bias, a1 = 0.f, a2 = 0.f, a3 = 0.f;
#pragma unroll
    for (int q = 0; q < 25; ++q) {
      float4 x4 = *reinterpret_cast<const float4*>(&xp[4 * q]);
      a0 = fmaf(Af[q * 4 + 0], x4.x, a0);
      a1 = fmaf(Af[q * 4 + 1], x4.y, a1);
      a2 = fmaf(Af[q * 4 + 2], x4.z, a2);
      a3 = fmaf(Af[q * 4 + 3], x4.w, a3);
    }
    Gd[(v0 + vi) * 256 + tid] = (a0 + a1) + (a2 + a3);
  }
}

// ============ K2: BiLSTM recurrence. 1 block = (b, dir), 4 waves ============
// lane l: unit u = w*16 + (l>>2), K-quarter kq = l&3. All 4 gates per lane.
// Whh slice held in 64 VGPRs via static-index asm pin (VGPR_Count must rise
// to ~110+; 56 = reload-per-step, the round-3..6 bottleneck).
// h broadcast: 4 ds_read_b128/wave; combine via DPP quad_perm (VALU pipe).
// Raw s_barrier (lgkmcnt-only drain) keeps G prefetch loads in flight.
__global__ __launch_bounds__(256, 2) void k2_lstm(
    const int* __restrict__ data,
    const float* __restrict__ G,
    const float* __restrict__ Whh_f,
    const float* __restrict__ Whh_b,
    float* __restrict__ hout)
{
  __shared__ __align__(16) float hls[2][64];
  int bid = blockIdx.x;
  int b = bid & 255;
  int dir = bid >> 8;
  int tid = threadIdx.x;
  int w = tid >> 6, l = tid & 63;
  int ul = l >> 2;           // 0..15
  int kq = l & 3;            // K-quarter
  int u = (w << 4) + ul;     // 0..63
  const float* Whh = dir ? Whh_b : Whh_f;

  // Wf[g*16 + kk]: gate g's row, K-slice [kq*16, kq*16+16)
  float Wf[64];
#pragma unroll
  for (int g = 0; g < 4; ++g) {
    const float4* wp = reinterpret_cast<const float4*>(Whh + ((g << 6) + u) * 64 + (kq << 4));
#pragma unroll
    for (int q = 0; q < 4; ++q) {
      float4 v = wp[q];
      Wf[g * 16 + q * 4 + 0] = v.x;
      Wf[g * 16 + q * 4 + 1] = v.y;
      Wf[g * 16 + q * 4 + 2] = v.z;
      Wf[g * 16 + q * 4 + 3] = v.w;
    }
  }
  PIN16(Wf, 0); PIN16(Wf, 16); PIN16(Wf, 32); PIN16(Wf, 48);

  if (tid < 64) hls[0][tid] = 0.0f;
  float c = 0.0f;
  const int* tokp = data + b * T_;
  const float* Gd = G + (size_t)dir * V_ * 256;
  float* hob = hout + ((size_t)(dir * B_ + b)) * T_ * H_;
  const float L2E = 1.4426950408889634f;

  // 3-ahead G prefetch ring
  float4 gq0 = *reinterpret_cast<const float4*>(&Gd[(size_t)tokp[dir ? (T_ - 1) : 0] * 256 + (u << 2)]);
  float4 gq1 = *reinterpret_cast<const float4*>(&Gd[(size_t)tokp[dir ? (T_ - 2) : 1] * 256 + (u << 2)]);
  float4 gq2 = *reinterpret_cast<const float4*>(&Gd[(size_t)tokp[dir ? (T_ - 3) : 2] * 256 + (u << 2)]);
  __syncthreads();

  int cur = 0;
  for (int s = 0; s < T_; ++s) {
    int tt = dir ? (T_ - 1 - s) : s;
    float4 gq3 = make_float4(0.f, 0.f, 0.f, 0.f);
    if (s < T_ - 3) {
      int ttn = dir ? (T_ - 4 - s) : (s + 3);
      gq3 = *reinterpret_cast<const float4*>(&Gd[(size_t)tokp[ttn] * 256 + (u << 2)]);
    }
    const float* hq = hls[cur] + (kq << 4);
    float4 h4[4];
#pragma unroll
    for (int q = 0; q < 4; ++q) h4[q] = *reinterpret_cast<const float4*>(&hq[q * 4]);
    float acc[4];
#pragma unroll
    for (int g = 0; g < 4; ++g) {
      float b0 = 0.f, b1 = 0.f, b2 = 0.f, b3 = 0.f;
#pragma unroll
      for (int q = 0; q < 4; ++q) {
        b0 = fmaf(Wf[g * 16 + q * 4 + 0], h4[q].x, b0);
        b1 = fmaf(Wf[g * 16 + q * 4 + 1], h4[q].y, b1);
        b2 = fmaf(Wf[g * 16 + q * 4 + 2], h4[q].z, b2);
        b3 = fmaf(Wf[g * 16 + q * 4 + 3], h4[q].w, b3);
      }
      acc[g] = (b0 + b1) + (b2 + b3);
    }
    // quad butterfly (DPP, no DS ops): every lane gets full 64-sum per gate
    float t0 = acc[0] + qp_xor1(acc[0]); float f0 = t0 + qp_xor2(t0);
    float t1 = acc[1] + qp_xor1(acc[1]); float f1 = t1 + qp_xor2(t1);
    float t2 = acc[2] + qp_xor1(acc[2]); float f2 = t2 + qp_xor2(t2);
    float t3 = acc[3] + qp_xor1(acc[3]); float f3 = t3 + qp_xor2(t3);
    float xi = f0 + gq0.x;
    float xf = f1 + gq0.y;
    float xg = f2 + gq0.z;
    float xo = f3 + gq0.w;
    // same activation formulas as rounds 4/5/6 (verified absmax 0.0)
    float si = __builtin_amdgcn_rcpf(1.0f + __builtin_amdgcn_exp2f(xi * (-L2E)));
    float sf = __builtin_amdgcn_rcpf(1.0f + __builtin_amdgcn_exp2f(xf * (-L2E)));
    float tg = fmaf(2.0f, __builtin_amdgcn_rcpf(1.0f + __builtin_amdgcn_exp2f(xg * (-2.0f * L2E))), -1.0f);
    float so = __builtin_amdgcn_rcpf(1.0f + __builtin_amdgcn_exp2f(xo * (-L2E)));
    c = __fadd_rn(__fmul_rn(sf, c), __fmul_rn(si, tg));
    float tc = fmaf(2.0f, __builtin_amdgcn_rcpf(1.0f + __builtin_amdgcn_exp2f(c * (-2.0f * L2E))), -1.0f);
    float hn = __fmul_rn(so, tc);
    if (kq == 0) {
      hls[cur ^ 1][u] = hn;
      hob[tt * H_ + u] = hn;
    }
    // raw barrier: drain LDS only; global prefetch loads stay in flight
    asm volatile("s_waitcnt lgkmcnt(0)\n\ts_barrier" ::: "memory");
    cur ^= 1;
    gq0 = gq1; gq1 = gq2; gq2 = gq3;
  }
}

// ============ K3: emissions = [hf|hb] @ W_out.T + b_out ============
__global__ __launch_bounds__(256) void k3_emit(
    const float* __restrict__ hbuf,
    const float* __restrict__ W_out,
    const float* __restrict__ b_out,
    float* __restrict__ emit)
{
  __shared__ float hl[64][132];
  __shared__ float Wl[17][132];
  int tid = threadIdx.x;
  int p0 = blockIdx.x * 64;  // flat position base (b*T + t), 64 consecutive t
  const float* hf = hbuf;
  const float* hb = hbuf + (size_t)B_ * T_ * H_;
#pragma unroll
  for (int i = 0; i < 4; ++i) {
    int idx = tid + i * 256;       // float4 index among 1024
    int pos = idx >> 4, e4 = idx & 15;
    float4 v = reinterpret_cast<const float4*>(hf + (size_t)p0 * 64)[idx];
    *reinterpret_cast<float4*>(&hl[pos][e4 * 4]) = v;
    float4 v2 = reinterpret_cast<const float4*>(hb + (size_t)p0 * 64)[idx];
    *reinterpret_cast<float4*>(&hl[pos][64 + e4 * 4]) = v2;
  }
  for (int i = tid; i < 17 * 128; i += 256) {
    int k = i >> 7, e = i & 127;
    Wl[k][e] = W_out[i];
  }
  __syncthreads();

  int pos = tid >> 2, ks = tid & 3;
  float acc[5] = {0.f, 0.f, 0.f, 0.f, 0.f};
#pragma unroll
  for (int e4 = 0; e4 < 32; ++e4) {
    float4 x4 = *reinterpret_cast<const float4*>(&hl[pos][e4 * 4]);
#pragma unroll
    for (int kk = 0; kk < 5; ++kk) {
      int k = ks + kk * 4;
      if (k < K_) {
        float4 w4 = *reinterpret_cast<const float4*>(&Wl[k][e4 * 4]);
        acc[kk] = fmaf(x4.x, w4.x, acc[kk]);
        acc[kk] = fmaf(x4.y, w4.y, acc[kk]);
        acc[kk] = fmaf(x4.z, w4.z, acc[kk]);
        acc[kk] = fmaf(x4.w, w4.w, acc[kk]);
      }
    }
  }
#pragma unroll
  for (int kk = 0; kk < 5; ++kk) {
    int k = ks + kk * 4;
    if (k < K_)
      emit[(size_t)(p0 + pos) * K_ + k] = __fadd_rn(acc[kk], b_out[k]);
  }
}

// ============ K4: Viterbi forward. 1 wave per b; lane = (half ic, tag j) ============
#define AMAX(vA, iA, vB, iB) { bool tk_ = (vB) > (vA); if (tk_) { vA = (vB); iA = (iB); } }

__global__ __launch_bounds__(64) void k4_viterbi(
    const float* __restrict__ emit,
    const float* __restrict__ trans,
    const float* __restrict__ start_trans,
    const float* __restrict__ end_trans,
    u8* __restrict__ bp,
    int* __restrict__ last,
    float* __restrict__ out)
{
  int b = blockIdx.x;
  int l = threadIdx.x;
  int ic = l >> 5;
  int hbase = l & 32;
  int j = l & 31;
  int jc = (j < K_) ? j : 0;
  int i0 = ic ? 9 : 0;
  int cnt = ic ? 8 : 9;
  float tr[9];
#pragma unroll
  for (int q = 0; q < 9; ++q)
    tr[q] = (q < cnt) ? trans[(i0 + q) * K_ + jc] : -__builtin_inff();
  asm volatile("" : "+v"(tr[0]), "+v"(tr[1]), "+v"(tr[2]), "+v"(tr[3]),
                    "+v"(tr[4]), "+v"(tr[5]), "+v"(tr[6]), "+v"(tr[7]), "+v"(tr[8]));
  const float* eb = emit + (size_t)b * T_ * K_;
  float endt = end_trans[jc];
  float s = __fadd_rn(start_trans[jc], eb[jc]);
  u8* bpb = bp + (size_t)b * T_ * 32;
  // 4-deep emission prefetch ring
  float er0 = eb[1 * K_ + jc];
  float er1 = eb[2 * K_ + jc];
  float er2 = eb[3 * K_ + jc];
  float er3 = eb[4 * K_ + jc];

  for (int t = 1; t < T_; ++t) {
    float ej = er0;
    er0 = er1; er1 = er2; er2 = er3;
    if (t + 4 < T_) er3 = eb[(size_t)(t + 4) * K_ + jc];
    float sv[9];
#pragma unroll
    for (int q = 0; q < 9; ++q) sv[q] = __shfl(s, hbase + i0 + q, 64);
    // np rounding order: cand = (score_i + trans_ij) + emit_j
    float cd[9];
#pragma unroll
    for (int q = 0; q < 9; ++q) cd[q] = __fadd_rn(__fadd_rn(sv[q], tr[q]), ej);
    // tree argmax; strict > with left-priority == np first-index tie rule
    float v01 = cd[0]; int x01 = i0;     AMAX(v01, x01, cd[1], i0 + 1);
    float v23 = cd[2]; int x23 = i0 + 2; AMAX(v23, x23, cd[3], i0 + 3);
    float v45 = cd[4]; int x45 = i0 + 4; AMAX(v45, x45, cd[5], i0 + 5);
    float v67 = cd[6]; int x67 = i0 + 6; AMAX(v67, x67, cd[7], i0 + 7);
    AMAX(v01, x01, v23, x23);
    AMAX(v45, x45, v67, x67);
    AMAX(v01, x01, v45, x45);
    AMAX(v01, x01, cd[8], i0 + 8);
    float m = v01; int idx = x01;
    float m2 = __shfl_xor(m, 32, 64);
    int idx2 = __shfl_xor(idx, 32, 64);
    bool take = (m2 > m) || ((m2 == m) && (idx2 < idx));
    if (take) { m = m2; idx = idx2; }
    s = m;
    if (ic == 0 && j < K_) bpb[(size_t)(t - 1) * 32 + j] = (u8)idx;
  }
  float fin = __fadd_rn(s, endt);
  float bm = __shfl(fin, hbase, 64);
  int bi = 0;
#pragma unroll
  for (int jj = 1; jj < K_; ++jj) {
    float v = __shfl(fin, hbase + jj, 64);
    if (v > bm) { bm = v; bi = jj; }
  }
  if (l == 0) {
    out[b] = bm;
    last[b] = bi;
    out[256 + (size_t)b * T_ + (T_ - 1)] = (float)bi;
  }
}

// ============ K5: backtrace — 8-deep double-buffered prefetch ============
__global__ __launch_bounds__(64) void k5_backtrace(
    const u8* __restrict__ bp,
    const int* __restrict__ last,
    float* __restrict__ out)
{
  int b = blockIdx.x * 64 + threadIdx.x;
  const u8* base = bp + (size_t)b * T_ * 32;
  int tag = last[b];
  float* ob = out + 256 + (size_t)b * T_;
  uint4 A0[8], A1[8];
  u32 B0[8], B1[8];
#pragma unroll
  for (int q = 0; q < 8; ++q) {
    const u8* p = base + (size_t)(510 - q) * 32;
    A0[q] = *reinterpret_cast<const uint4*>(p);
    B0[q] = *reinterpret_cast<const u32*>(p + 16);
  }
  int t0 = 510;
  for (int pair = 0; pair < 32; ++pair) {
#pragma unroll
    for (int q = 0; q < 8; ++q) {
      int tn = t0 - 8 - q;
      if (tn >= 0) {
        const u8* p = base + (size_t)tn * 32;
        A1[q] = *reinterpret_cast<const uint4*>(p);
        B1[q] = *reinterpret_cast<const u32*>(p + 16);
      }
    }
#pragma unroll
    for (int q = 0; q < 8; ++q) {
      int t = t0 - q;
      if (t >= 0) {
        uint4 Av = A0[q]; u32 Bw = B0[q];
        u32 dw = (tag < 8) ? ((tag < 4) ? Av.x : Av.y) : ((tag < 12) ? Av.z : Av.w);
        dw = (tag < 16) ? dw : Bw;
        tag = (int)((dw >> ((tag & 3) * 8)) & 0xffu);
        ob[t] = (float)tag;
      }
    }
#pragma unroll
    for (int q = 0; q < 8; ++q) {
      int tn = t0 - 16 - q;
      if (tn >= 0) {
        const u8* p = base + (size_t)tn * 32;
        A0[q] = *reinterpret_cast<const uint4*>(p);
        B0[q] = *reinterpret_cast<const u32*>(p + 16);
      }
    }
#pragma unroll
    for (int q = 0; q < 8; ++q) {
      int t = t0 - 8 - q;
      if (t >= 0) {
        uint4 Av = A1[q]; u32 Bw = B1[q];
        u32 dw = (tag < 8) ? ((tag < 4) ? Av.x : Av.y) : ((tag < 12) ? Av.z : Av.w);
        dw = (tag < 16) ? dw : Bw;
        tag = (int)((dw >> ((tag & 3) * 8)) & 0xffu);
        ob[t] = (float)tag;
      }
    }
    t0 -= 16;
  }
}

extern "C" void kernel_launch(void* const* d_in, const int* in_sizes, int n_in,
                              void* d_out, int out_size, void* d_ws, size_t ws_size,
                              hipStream_t stream) {
  const int*   data  = (const int*)d_in[0];
  const float* emb   = (const float*)d_in[2];
  const float* Wih_f = (const float*)d_in[3];
  const float* Whh_f = (const float*)d_in[4];
  const float* bih_f = (const float*)d_in[5];
  const float* bhh_f = (const float*)d_in[6];
  const float* Wih_b = (const float*)d_in[7];
  const float* Whh_b = (const float*)d_in[8];
  const float* bih_b = (const float*)d_in[9];
  const float* bhh_b = (const float*)d_in[10];
  const float* W_out = (const float*)d_in[11];
  const float* b_out = (const float*)d_in[12];
  const float* trans = (const float*)d_in[13];
  const float* start_trans = (const float*)d_in[14];
  const float* end_trans   = (const float*)d_in[15];

  char* ws = (char*)d_ws;
  float* G    = (float*)(ws + WS_G);
  float* hbuf = (float*)(ws + WS_H);
  float* emit = (float*)(ws + WS_EMIT);
  u8*    bp   = (u8*)(ws + WS_BP);
  int*   lastp = (int*)(ws + WS_LAST);
  float* out = (float*)d_out;

  k1_build_G<<<dim3(250, 2), 256, 0, stream>>>(emb, Wih_f, bih_f, bhh_f,
                                               Wih_b, bih_b, bhh_b, G);
  k2_lstm<<<512, 256, 0, stream>>>(data, G, Whh_f, Whh_b, hbuf);
  k3_emit<<<2048, 256, 0, stream>>>(hbuf, W_out, b_out, emit);
  k4_viterbi<<<256, 64, 0, stream>>>(emit, trans, start_trans, end_trans,
                                     bp, lastp, out);
  k5_backtrace<<<4, 64, 0, stream>>>(bp, lastp, out);
}

// Round 8
// 679.235 us; speedup vs baseline: 1.0872x; 1.0094x over previous
//
#include <hip/hip_runtime.h>
#include <hip/hip_bf16.h>

typedef unsigned int u32;
typedef unsigned char u8;

#define B_ 256
#define T_ 512
#define E_ 100
#define H_ 64
#define K_ 17
#define V_ 8000

// ---- ws layout (bytes) ----
#define WS_G     0            // 2 * 8000 * 256 * 4 = 16,384,000
#define WS_H     16384000     // 2 * 256 * 512 * 64 * 4 = 67,108,864
#define WS_EMIT  83492864     // 131072 * 17 * 4 = 8,912,896
#define WS_BP    92405760     // 256 * 512 * 32 = 4,194,304
#define WS_LAST  96600064     // 256 * 4

// Pin one float4's components into VGPRs (asm result is non-rematerializable).
#define PINF4(v) asm volatile("" : "+v"((v).x), "+v"((v).y), "+v"((v).z), "+v"((v).w))

// quad_perm DPP: xor1 = [1,0,3,2] = 0xB1, xor2 = [2,3,0,1] = 0x4E
__device__ __forceinline__ float qp_xor1(float v) {
  int r = __builtin_amdgcn_update_dpp(0, __builtin_bit_cast(int, v), 0xB1, 0xF, 0xF, true);
  return __builtin_bit_cast(float, r);
}
__device__ __forceinline__ float qp_xor2(float v) {
  int r = __builtin_amdgcn_update_dpp(0, __builtin_bit_cast(int, v), 0x4E, 0xF, 0xF, true);
  return __builtin_bit_cast(float, r);
}

// ============ K1: G[v][u*4+g] = emb[v] @ Wih[g*64+u].T + bih + bhh ============
// amdgpu_waves_per_eu(2,2): backend otherwise targets 8 waves/EU (VGPR<=64)
// and demotes the 100 loop-invariant weights to per-iteration reloads.
__global__ __launch_bounds__(256)
__attribute__((amdgpu_waves_per_eu(2, 2)))
void k1_build_G(
    const float* __restrict__ emb,
    const float* __restrict__ Wih_f,
    const float* __restrict__ bih_f,
    const float* __restrict__ bhh_f,
    const float* __restrict__ Wih_b,
    const float* __restrict__ bih_b,
    const float* __restrict__ bhh_b,
    float* __restrict__ G)
{
  __shared__ float xl[32 * E_];
  int v0 = blockIdx.x * 32;
  int dir = blockIdx.y;
  int tid = threadIdx.x;
  const float* Wih = dir ? Wih_b : Wih_f;
  const float* bih = dir ? bih_b : bih_f;
  const float* bhh = dir ? bhh_b : bhh_f;

  for (int i = tid; i < 32 * E_; i += 256) xl[i] = emb[v0 * E_ + i];

  int u = tid >> 2, g = tid & 3;
  int row = (g << 6) + u;
  const float* wr = Wih + row * E_;   // 400B rows, 16B aligned
#define LDA(name, q) float4 name = *reinterpret_cast<const float4*>(wr + 4 * (q)); PINF4(name)
  LDA(A0,0);  LDA(A1,1);  LDA(A2,2);  LDA(A3,3);  LDA(A4,4);
  LDA(A5,5);  LDA(A6,6);  LDA(A7,7);  LDA(A8,8);  LDA(A9,9);
  LDA(A10,10);LDA(A11,11);LDA(A12,12);LDA(A13,13);LDA(A14,14);
  LDA(A15,15);LDA(A16,16);LDA(A17,17);LDA(A18,18);LDA(A19,19);
  LDA(A20,20);LDA(A21,21);LDA(A22,22);LDA(A23,23);LDA(A24,24);
#undef LDA
  float bias = __fadd_rn(bih[row], bhh[row]);
  __syncthreads();

  float* Gd = G + (size_t)dir * V_ * 256;
  for (int vi = 0; vi < 32; ++vi) {
    const float* xp = &xl[vi * E_];   // vi*400B, 16B aligned
    float a0 = bias, a1 = 0.f, a2 = 0.f, a3 = 0.f;
#define K1F(Aq, q) { float4 x4 = *reinterpret_cast<const float4*>(xp + 4 * (q)); \
    a0 = fmaf(Aq.x, x4.x, a0); a1 = fmaf(Aq.y, x4.y, a1); \
    a2 = fmaf(Aq.z, x4.z, a2); a3 = fmaf(Aq.w, x4.w, a3); }
    K1F(A0,0)  K1F(A1,1)  K1F(A2,2)  K1F(A3,3)  K1F(A4,4)
    K1F(A5,5)  K1F(A6,6)  K1F(A7,7)  K1F(A8,8)  K1F(A9,9)
    K1F(A10,10)K1F(A11,11)K1F(A12,12)K1F(A13,13)K1F(A14,14)
    K1F(A15,15)K1F(A16,16)K1F(A17,17)K1F(A18,18)K1F(A19,19)
    K1F(A20,20)K1F(A21,21)K1F(A22,22)K1F(A23,23)K1F(A24,24)
#undef K1F
    Gd[(v0 + vi) * 256 + tid] = (a0 + a1) + (a2 + a3);
  }
}

// ============ K2: BiLSTM recurrence. 1 block = (b, dir), 4 waves ============
// lane l: unit u = w*16 + (l>>2), K-quarter kq = l&3. All 4 gates per lane.
// 64 weights in 16 NAMED float4s (no arrays -> SROA trivial), pinned, and
// amdgpu_waves_per_eu(2,2) so the allocator stops targeting 8 waves/EU
// (the round-3..7 bottleneck: VGPR pinned at 52-60 => per-step reloads).
// h broadcast: 4 ds_read_b128/wave; combine via DPP quad_perm (VALU pipe).
// Raw s_barrier (lgkmcnt-only drain) keeps G prefetch loads in flight.
__global__ __launch_bounds__(256)
__attribute__((amdgpu_waves_per_eu(2, 2)))
void k2_lstm(
    const int* __restrict__ data,
    const float* __restrict__ G,
    const float* __restrict__ Whh_f,
    const float* __restrict__ Whh_b,
    float* __restrict__ hout)
{
  __shared__ __align__(16) float hls[2][64];
  int bid = blockIdx.x;
  int b = bid & 255;
  int dir = bid >> 8;
  int tid = threadIdx.x;
  int w = tid >> 6, l = tid & 63;
  int ul = l >> 2;           // 0..15
  int kq = l & 3;            // K-quarter
  int u = (w << 4) + ul;     // 0..63
  const float* Whh = dir ? Whh_b : Whh_f;
  const float* wb = Whh + u * 64 + (kq << 4);   // gate g at +g*4096, quad q at +4q

#define LDW(name, g, q) float4 name = *reinterpret_cast<const float4*>(wb + (g) * 4096 + 4 * (q)); PINF4(name)
  LDW(W00,0,0); LDW(W01,0,1); LDW(W02,0,2); LDW(W03,0,3);
  LDW(W10,1,0); LDW(W11,1,1); LDW(W12,1,2); LDW(W13,1,3);
  LDW(W20,2,0); LDW(W21,2,1); LDW(W22,2,2); LDW(W23,2,3);
  LDW(W30,3,0); LDW(W31,3,1); LDW(W32,3,2); LDW(W33,3,3);
#undef LDW

  if (tid < 64) hls[0][tid] = 0.0f;
  float c = 0.0f;
  const int* tokp = data + b * T_;
  const float* Gd = G + (size_t)dir * V_ * 256;
  float* hob = hout + ((size_t)(dir * B_ + b)) * T_ * H_;
  const float L2E = 1.4426950408889634f;

  // 3-ahead G prefetch ring
  float4 gq0 = *reinterpret_cast<const float4*>(&Gd[(size_t)tokp[dir ? (T_ - 1) : 0] * 256 + (u << 2)]);
  float4 gq1 = *reinterpret_cast<const float4*>(&Gd[(size_t)tokp[dir ? (T_ - 2) : 1] * 256 + (u << 2)]);
  float4 gq2 = *reinterpret_cast<const float4*>(&Gd[(size_t)tokp[dir ? (T_ - 3) : 2] * 256 + (u << 2)]);
  __syncthreads();

  int cur = 0;
  for (int s = 0; s < T_; ++s) {
    int tt = dir ? (T_ - 1 - s) : s;
    float4 gq3 = make_float4(0.f, 0.f, 0.f, 0.f);
    if (s < T_ - 3) {
      int ttn = dir ? (T_ - 4 - s) : (s + 3);
      gq3 = *reinterpret_cast<const float4*>(&Gd[(size_t)tokp[ttn] * 256 + (u << 2)]);
    }
    const float* hq = hls[cur] + (kq << 4);
    float4 h0 = *reinterpret_cast<const float4*>(hq + 0);
    float4 h1 = *reinterpret_cast<const float4*>(hq + 4);
    float4 h2 = *reinterpret_cast<const float4*>(hq + 8);
    float4 h3 = *reinterpret_cast<const float4*>(hq + 12);
    // per-gate 16-elem dot; first term fmaf(a,b,0) == a*b bit-exact
#define GDOT(res, Wa, Wb, Wc, Wd) float res; { \
    float b0 = Wa.x * h0.x; float b1 = Wa.y * h0.y; float b2 = Wa.z * h0.z; float b3 = Wa.w * h0.w; \
    b0 = fmaf(Wb.x, h1.x, b0); b1 = fmaf(Wb.y, h1.y, b1); b2 = fmaf(Wb.z, h1.z, b2); b3 = fmaf(Wb.w, h1.w, b3); \
    b0 = fmaf(Wc.x, h2.x, b0); b1 = fmaf(Wc.y, h2.y, b1); b2 = fmaf(Wc.z, h2.z, b2); b3 = fmaf(Wc.w, h2.w, b3); \
    b0 = fmaf(Wd.x, h3.x, b0); b1 = fmaf(Wd.y, h3.y, b1); b2 = fmaf(Wd.z, h3.z, b2); b3 = fmaf(Wd.w, h3.w, b3); \
    res = (b0 + b1) + (b2 + b3); }
    GDOT(acc0, W00, W01, W02, W03)
    GDOT(acc1, W10, W11, W12, W13)
    GDOT(acc2, W20, W21, W22, W23)
    GDOT(acc3, W30, W31, W32, W33)
#undef GDOT
    // quad butterfly (DPP, no DS ops): every lane gets full 64-sum per gate
    float t0 = acc0 + qp_xor1(acc0); float f0 = t0 + qp_xor2(t0);
    float t1 = acc1 + qp_xor1(acc1); float f1 = t1 + qp_xor2(t1);
    float t2 = acc2 + qp_xor1(acc2); float f2 = t2 + qp_xor2(t2);
    float t3 = acc3 + qp_xor1(acc3); float f3 = t3 + qp_xor2(t3);
    float xi = f0 + gq0.x;
    float xf = f1 + gq0.y;
    float xg = f2 + gq0.z;
    float xo = f3 + gq0.w;
    // same activation formulas as rounds 4-7 (verified absmax 0.0)
    float si = __builtin_amdgcn_rcpf(1.0f + __builtin_amdgcn_exp2f(xi * (-L2E)));
    float sf = __builtin_amdgcn_rcpf(1.0f + __builtin_amdgcn_exp2f(xf * (-L2E)));
    float tg = fmaf(2.0f, __builtin_amdgcn_rcpf(1.0f + __builtin_amdgcn_exp2f(xg * (-2.0f * L2E))), -1.0f);
    float so = __builtin_amdgcn_rcpf(1.0f + __builtin_amdgcn_exp2f(xo * (-L2E)));
    c = __fadd_rn(__fmul_rn(sf, c), __fmul_rn(si, tg));
    float tc = fmaf(2.0f, __builtin_amdgcn_rcpf(1.0f + __builtin_amdgcn_exp2f(c * (-2.0f * L2E))), -1.0f);
    float hn = __fmul_rn(so, tc);
    if (kq == 0) {
      hls[cur ^ 1][u] = hn;
      hob[tt * H_ + u] = hn;
    }
    // raw barrier: drain LDS only; global prefetch loads stay in flight
    asm volatile("s_waitcnt lgkmcnt(0)\n\ts_barrier" ::: "memory");
    cur ^= 1;
    gq0 = gq1; gq1 = gq2; gq2 = gq3;
  }
}

// ============ K3: emissions = [hf|hb] @ W_out.T + b_out ============
__global__ __launch_bounds__(256) void k3_emit(
    const float* __restrict__ hbuf,
    const float* __restrict__ W_out,
    const float* __restrict__ b_out,
    float* __restrict__ emit)
{
  __shared__ float hl[64][132];
  __shared__ float Wl[17][132];
  int tid = threadIdx.x;
  int p0 = blockIdx.x * 64;  // flat position base (b*T + t), 64 consecutive t
  const float* hf = hbuf;
  const float* hb = hbuf + (size_t)B_ * T_ * H_;
#pragma unroll
  for (int i = 0; i < 4; ++i) {
    int idx = tid + i * 256;       // float4 index among 1024
    int pos = idx >> 4, e4 = idx & 15;
    float4 v = reinterpret_cast<const float4*>(hf + (size_t)p0 * 64)[idx];
    *reinterpret_cast<float4*>(&hl[pos][e4 * 4]) = v;
    float4 v2 = reinterpret_cast<const float4*>(hb + (size_t)p0 * 64)[idx];
    *reinterpret_cast<float4*>(&hl[pos][64 + e4 * 4]) = v2;
  }
  for (int i = tid; i < 17 * 128; i += 256) {
    int k = i >> 7, e = i & 127;
    Wl[k][e] = W_out[i];
  }
  __syncthreads();

  int pos = tid >> 2, ks = tid & 3;
  float acc[5] = {0.f, 0.f, 0.f, 0.f, 0.f};
#pragma unroll
  for (int e4 = 0; e4 < 32; ++e4) {
    float4 x4 = *reinterpret_cast<const float4*>(&hl[pos][e4 * 4]);
#pragma unroll
    for (int kk = 0; kk < 5; ++kk) {
      int k = ks + kk * 4;
      if (k < K_) {
        float4 w4 = *reinterpret_cast<const float4*>(&Wl[k][e4 * 4]);
        acc[kk] = fmaf(x4.x, w4.x, acc[kk]);
        acc[kk] = fmaf(x4.y, w4.y, acc[kk]);
        acc[kk] = fmaf(x4.z, w4.z, acc[kk]);
        acc[kk] = fmaf(x4.w, w4.w, acc[kk]);
      }
    }
  }
#pragma unroll
  for (int kk = 0; kk < 5; ++kk) {
    int k = ks + kk * 4;
    if (k < K_)
      emit[(size_t)(p0 + pos) * K_ + k] = __fadd_rn(acc[kk], b_out[k]);
  }
}

// ============ K4: Viterbi forward. 1 wave per b; lane = (half ic, tag j) ============
#define AMAX(vA, iA, vB, iB) { bool tk_ = (vB) > (vA); if (tk_) { vA = (vB); iA = (iB); } }

__global__ __launch_bounds__(64) void k4_viterbi(
    const float* __restrict__ emit,
    const float* __restrict__ trans,
    const float* __restrict__ start_trans,
    const float* __restrict__ end_trans,
    u8* __restrict__ bp,
    int* __restrict__ last,
    float* __restrict__ out)
{
  int b = blockIdx.x;
  int l = threadIdx.x;
  int ic = l >> 5;
  int hbase = l & 32;
  int j = l & 31;
  int jc = (j < K_) ? j : 0;
  int i0 = ic ? 9 : 0;
  int cnt = ic ? 8 : 9;
  // named scalars (no array -> no SROA hazard)
  float tr0 = trans[(i0 + 0) * K_ + jc];
  float tr1 = trans[(i0 + 1) * K_ + jc];
  float tr2 = trans[(i0 + 2) * K_ + jc];
  float tr3 = trans[(i0 + 3) * K_ + jc];
  float tr4 = trans[(i0 + 4) * K_ + jc];
  float tr5 = trans[(i0 + 5) * K_ + jc];
  float tr6 = trans[(i0 + 6) * K_ + jc];
  float tr7 = trans[(i0 + 7) * K_ + jc];
  float tr8 = (cnt > 8) ? trans[(i0 + 8) * K_ + jc] : -__builtin_inff();
  asm volatile("" : "+v"(tr0), "+v"(tr1), "+v"(tr2), "+v"(tr3), "+v"(tr4),
                    "+v"(tr5), "+v"(tr6), "+v"(tr7), "+v"(tr8));
  const float* eb = emit + (size_t)b * T_ * K_;
  float endt = end_trans[jc];
  float s = __fadd_rn(start_trans[jc], eb[jc]);
  u8* bpb = bp + (size_t)b * T_ * 32;
  // 4-deep emission prefetch ring
  float er0 = eb[1 * K_ + jc];
  float er1 = eb[2 * K_ + jc];
  float er2 = eb[3 * K_ + jc];
  float er3 = eb[4 * K_ + jc];

  for (int t = 1; t < T_; ++t) {
    float ej = er0;
    er0 = er1; er1 = er2; er2 = er3;
    if (t + 4 < T_) er3 = eb[(size_t)(t + 4) * K_ + jc];
    float p0 = __shfl(s, hbase + i0 + 0, 64);
    float p1 = __shfl(s, hbase + i0 + 1, 64);
    float p2 = __shfl(s, hbase + i0 + 2, 64);
    float p3 = __shfl(s, hbase + i0 + 3, 64);
    float p4 = __shfl(s, hbase + i0 + 4, 64);
    float p5 = __shfl(s, hbase + i0 + 5, 64);
    float p6 = __shfl(s, hbase + i0 + 6, 64);
    float p7 = __shfl(s, hbase + i0 + 7, 64);
    float p8 = __shfl(s, hbase + i0 + 8, 64);
    // np rounding order: cand = (score_i + trans_ij) + emit_j
    float c0 = __fadd_rn(__fadd_rn(p0, tr0), ej);
    float c1 = __fadd_rn(__fadd_rn(p1, tr1), ej);
    float c2 = __fadd_rn(__fadd_rn(p2, tr2), ej);
    float c3 = __fadd_rn(__fadd_rn(p3, tr3), ej);
    float c4 = __fadd_rn(__fadd_rn(p4, tr4), ej);
    float c5 = __fadd_rn(__fadd_rn(p5, tr5), ej);
    float c6 = __fadd_rn(__fadd_rn(p6, tr6), ej);
    float c7 = __fadd_rn(__fadd_rn(p7, tr7), ej);
    float c8 = __fadd_rn(__fadd_rn(p8, tr8), ej);
    // tree argmax; strict > with left-priority == np first-index tie rule
    float v01 = c0; int x01 = i0;     AMAX(v01, x01, c1, i0 + 1);
    float v23 = c2; int x23 = i0 + 2; AMAX(v23, x23, c3, i0 + 3);
    float v45 = c4; int x45 = i0 + 4; AMAX(v45, x45, c5, i0 + 5);
    float v67 = c6; int x67 = i0 + 6; AMAX(v67, x67, c7, i0 + 7);
    AMAX(v01, x01, v23, x23);
    AMAX(v45, x45, v67, x67);
    AMAX(v01, x01, v45, x45);
    AMAX(v01, x01, c8, i0 + 8);
    float m = v01; int idx = x01;
    float m2 = __shfl_xor(m, 32, 64);
    int idx2 = __shfl_xor(idx, 32, 64);
    bool take = (m2 > m) || ((m2 == m) && (idx2 < idx));
    if (take) { m = m2; idx = idx2; }
    s = m;
    if (ic == 0 && j < K_) bpb[(size_t)(t - 1) * 32 + j] = (u8)idx;
  }
  float fin = __fadd_rn(s, endt);
  float bm = __shfl(fin, hbase, 64);
  int bi = 0;
#pragma unroll
  for (int jj = 1; jj < K_; ++jj) {
    float v = __shfl(fin, hbase + jj, 64);
    if (v > bm) { bm = v; bi = jj; }
  }
  if (l == 0) {
    out[b] = bm;
    last[b] = bi;
    out[256 + (size_t)b * T_ + (T_ - 1)] = (float)bi;
  }
}

// ============ K5: backtrace — 8-deep double-buffered prefetch ============
__global__ __launch_bounds__(64) void k5_backtrace(
    const u8* __restrict__ bp,
    const int* __restrict__ last,
    float* __restrict__ out)
{
  int b = blockIdx.x * 64 + threadIdx.x;
  const u8* base = bp + (size_t)b * T_ * 32;
  int tag = last[b];
  float* ob = out + 256 + (size_t)b * T_;
  uint4 A0[8], A1[8];
  u32 B0[8], B1[8];
#pragma unroll
  for (int q = 0; q < 8; ++q) {
    const u8* p = base + (size_t)(510 - q) * 32;
    A0[q] = *reinterpret_cast<const uint4*>(p);
    B0[q] = *reinterpret_cast<const u32*>(p + 16);
  }
  int t0 = 510;
  for (int pair = 0; pair < 32; ++pair) {
#pragma unroll
    for (int q = 0; q < 8; ++q) {
      int tn = t0 - 8 - q;
      if (tn >= 0) {
        const u8* p = base + (size_t)tn * 32;
        A1[q] = *reinterpret_cast<const uint4*>(p);
        B1[q] = *reinterpret_cast<const u32*>(p + 16);
      }
    }
#pragma unroll
    for (int q = 0; q < 8; ++q) {
      int t = t0 - q;
      if (t >= 0) {
        uint4 Av = A0[q]; u32 Bw = B0[q];
        u32 dw = (tag < 8) ? ((tag < 4) ? Av.x : Av.y) : ((tag < 12) ? Av.z : Av.w);
        dw = (tag < 16) ? dw : Bw;
        tag = (int)((dw >> ((tag & 3) * 8)) & 0xffu);
        ob[t] = (float)tag;
      }
    }
#pragma unroll
    for (int q = 0; q < 8; ++q) {
      int tn = t0 - 16 - q;
      if (tn >= 0) {
        const u8* p = base + (size_t)tn * 32;
        A0[q] = *reinterpret_cast<const uint4*>(p);
        B0[q] = *reinterpret_cast<const u32*>(p + 16);
      }
    }
#pragma unroll
    for (int q = 0; q < 8; ++q) {
      int t = t0 - 8 - q;
      if (t >= 0) {
        uint4 Av = A1[q]; u32 Bw = B1[q];
        u32 dw = (tag < 8) ? ((tag < 4) ? Av.x : Av.y) : ((tag < 12) ? Av.z : Av.w);
        dw = (tag < 16) ? dw : Bw;
        tag = (int)((dw >> ((tag & 3) * 8)) & 0xffu);
        ob[t] = (float)tag;
      }
    }
    t0 -= 16;
  }
}

extern "C" void kernel_launch(void* const* d_in, const int* in_sizes, int n_in,
                              void* d_out, int out_size, void* d_ws, size_t ws_size,
                              hipStream_t stream) {
  const int*   data  = (const int*)d_in[0];
  const float* emb   = (const float*)d_in[2];
  const float* Wih_f = (const float*)d_in[3];
  const float* Whh_f = (const float*)d_in[4];
  const float* bih_f = (const float*)d_in[5];
  const float* bhh_f = (const float*)d_in[6];
  const float* Wih_b = (const float*)d_in[7];
  const float* Whh_b = (const float*)d_in[8];
  const float* bih_b = (const float*)d_in[9];
  const float* bhh_b = (const float*)d_in[10];
  const float* W_out = (const float*)d_in[11];
  const float* b_out = (const float*)d_in[12];
  const float* trans = (const float*)d_in[13];
  const float* start_trans = (const float*)d_in[14];
  const float* end_trans   = (const float*)d_in[15];

  char* ws = (char*)d_ws;
  float* G    = (float*)(ws + WS_G);
  float* hbuf = (float*)(ws + WS_H);
  float* emit = (float*)(ws + WS_EMIT);
  u8*    bp   = (u8*)(ws + WS_BP);
  int*   lastp = (int*)(ws + WS_LAST);
  float* out = (float*)d_out;

  k1_build_G<<<dim3(250, 2), 256, 0, stream>>>(emb, Wih_f, bih_f, bhh_f,
                                               Wih_b, bih_b, bhh_b, G);
  k2_lstm<<<512, 256, 0, stream>>>(data, G, Whh_f, Whh_b, hbuf);
  k3_emit<<<2048, 256, 0, stream>>>(hbuf, W_out, b_out, emit);
  k4_viterbi<<<256, 64, 0, stream>>>(emit, trans, start_trans, end_trans,
                                     bp, lastp, out);
  k5_backtrace<<<4, 64, 0, stream>>>(bp, lastp, out);
}

// Round 9
// 668.230 us; speedup vs baseline: 1.1051x; 1.0165x over previous
//
#include <hip/hip_runtime.h>
#include <hip/hip_bf16.h>

typedef unsigned int u32;
typedef unsigned char u8;

#define B_ 256
#define T_ 512
#define E_ 100
#define H_ 64
#define K_ 17
#define V_ 8000

// ---- ws layout (bytes) ----
#define WS_G     0            // 2 * 8000 * 256 * 4 = 16,384,000
#define WS_H     16384000     // 2 * 256 * 512 * 64 * 4 = 67,108,864
#define WS_EMIT  83492864     // 131072 * 17 * 4 = 8,912,896
#define WS_BP    92405760     // 256 * 512 * 32 = 4,194,304
#define WS_LAST  96600064     // 256 * 4

// Pin one float4's components into VGPRs (asm result is non-rematerializable).
#define PINF4(v) asm volatile("" : "+v"((v).x), "+v"((v).y), "+v"((v).z), "+v"((v).w))

// quad_perm DPP: xor1 = [1,0,3,2] = 0xB1, xor2 = [2,3,0,1] = 0x4E
__device__ __forceinline__ float qp_xor1(float v) {
  int r = __builtin_amdgcn_update_dpp(0, __builtin_bit_cast(int, v), 0xB1, 0xF, 0xF, true);
  return __builtin_bit_cast(float, r);
}
__device__ __forceinline__ float qp_xor2(float v) {
  int r = __builtin_amdgcn_update_dpp(0, __builtin_bit_cast(int, v), 0x4E, 0xF, 0xF, true);
  return __builtin_bit_cast(float, r);
}

// ============ K1: G[v][u*4+g] = emb[v] @ Wih[g*64+u].T + bih + bhh ============
__global__ __launch_bounds__(256)
__attribute__((amdgpu_waves_per_eu(2, 2)))
void k1_build_G(
    const float* __restrict__ emb,
    const float* __restrict__ Wih_f,
    const float* __restrict__ bih_f,
    const float* __restrict__ bhh_f,
    const float* __restrict__ Wih_b,
    const float* __restrict__ bih_b,
    const float* __restrict__ bhh_b,
    float* __restrict__ G)
{
  __shared__ float xl[32 * E_];
  int v0 = blockIdx.x * 32;
  int dir = blockIdx.y;
  int tid = threadIdx.x;
  const float* Wih = dir ? Wih_b : Wih_f;
  const float* bih = dir ? bih_b : bih_f;
  const float* bhh = dir ? bhh_b : bhh_f;

  for (int i = tid; i < 32 * E_; i += 256) xl[i] = emb[v0 * E_ + i];

  int u = tid >> 2, g = tid & 3;
  int row = (g << 6) + u;
  const float* wr = Wih + row * E_;   // 400B rows, 16B aligned
#define LDA(name, q) float4 name = *reinterpret_cast<const float4*>(wr + 4 * (q)); PINF4(name)
  LDA(A0,0);  LDA(A1,1);  LDA(A2,2);  LDA(A3,3);  LDA(A4,4);
  LDA(A5,5);  LDA(A6,6);  LDA(A7,7);  LDA(A8,8);  LDA(A9,9);
  LDA(A10,10);LDA(A11,11);LDA(A12,12);LDA(A13,13);LDA(A14,14);
  LDA(A15,15);LDA(A16,16);LDA(A17,17);LDA(A18,18);LDA(A19,19);
  LDA(A20,20);LDA(A21,21);LDA(A22,22);LDA(A23,23);LDA(A24,24);
#undef LDA
  float bias = __fadd_rn(bih[row], bhh[row]);
  __syncthreads();

  float* Gd = G + (size_t)dir * V_ * 256;
  for (int vi = 0; vi < 32; ++vi) {
    const float* xp = &xl[vi * E_];   // vi*400B, 16B aligned
    float a0 = bias, a1 = 0.f, a2 = 0.f, a3 = 0.f;
#define K1F(Aq, q) { float4 x4 = *reinterpret_cast<const float4*>(xp + 4 * (q)); \
    a0 = fmaf(Aq.x, x4.x, a0); a1 = fmaf(Aq.y, x4.y, a1); \
    a2 = fmaf(Aq.z, x4.z, a2); a3 = fmaf(Aq.w, x4.w, a3); }
    K1F(A0,0)  K1F(A1,1)  K1F(A2,2)  K1F(A3,3)  K1F(A4,4)
    K1F(A5,5)  K1F(A6,6)  K1F(A7,7)  K1F(A8,8)  K1F(A9,9)
    K1F(A10,10)K1F(A11,11)K1F(A12,12)K1F(A13,13)K1F(A14,14)
    K1F(A15,15)K1F(A16,16)K1F(A17,17)K1F(A18,18)K1F(A19,19)
    K1F(A20,20)K1F(A21,21)K1F(A22,22)K1F(A23,23)K1F(A24,24)
#undef K1F
    Gd[(v0 + vi) * 256 + tid] = (a0 + a1) + (a2 + a3);
  }
}

// ============ K2: BiLSTM recurrence. 1 block = (b, dir), 4 waves ============
// Latency-chain redesign (round-8 post-mortem: latency-bound, not
// throughput/residency): tokens staged to LDS in STEP ORDER (no per-step
// global token load), next token register-carried across the barrier
// (ds_read completes under the lgkmcnt(0) drain), row base scalarized via
// readfirstlane (saddr-form load), 4-deep G ring, branch-free tail (token
// pad=0 -> harmless row-0 load), stepped hout pointer.
__global__ __launch_bounds__(256)
__attribute__((amdgpu_waves_per_eu(2, 2)))
void k2_lstm(
    const int* __restrict__ data,
    const float* __restrict__ G,
    const float* __restrict__ Whh_f,
    const float* __restrict__ Whh_b,
    float* __restrict__ hout)
{
  __shared__ __align__(16) float hls[2][64];
  __shared__ int tok_lds[T_ + 8];
  int bid = blockIdx.x;
  int b = bid & 255;
  int dir = bid >> 8;
  int tid = threadIdx.x;
  int w = tid >> 6, l = tid & 63;
  int ul = l >> 2;           // 0..15
  int kq = l & 3;            // K-quarter
  int u = (w << 4) + ul;     // 0..63
  const float* Whh = dir ? Whh_b : Whh_f;
  const float* wb = Whh + u * 64 + (kq << 4);   // gate g at +g*4096, quad q at +4q

#define LDW(name, g, q) float4 name = *reinterpret_cast<const float4*>(wb + (g) * 4096 + 4 * (q)); PINF4(name)
  LDW(W00,0,0); LDW(W01,0,1); LDW(W02,0,2); LDW(W03,0,3);
  LDW(W10,1,0); LDW(W11,1,1); LDW(W12,1,2); LDW(W13,1,3);
  LDW(W20,2,0); LDW(W21,2,1); LDW(W22,2,2); LDW(W23,2,3);
  LDW(W30,3,0); LDW(W31,3,1); LDW(W32,3,2); LDW(W33,3,3);
#undef LDW

  // stage tokens in step order (dir-reversed for bwd); pad tail with 0
  const int* tokp = data + b * T_;
  for (int i = tid; i < T_; i += 256)
    tok_lds[i] = tokp[dir ? (T_ - 1 - i) : i];
  if (tid < 8) tok_lds[T_ + tid] = 0;
  if (tid < 64) hls[0][tid] = 0.0f;
  __syncthreads();

  float c = 0.0f;
  const float* Gd = G + (size_t)dir * V_ * 256;
  float* hob = hout + ((size_t)(dir * B_ + b)) * T_ * H_;
  float* hop = hob + (dir ? (T_ - 1) * H_ : 0) + u;
  int hstep = dir ? -H_ : H_;
  const float L2E = 1.4426950408889634f;

  // 4-deep G ring: rows for steps 0..3 (tokens block-uniform -> saddr loads)
  float4 gq0, gq1, gq2, gq3;
  {
    int t0 = __builtin_amdgcn_readfirstlane(tok_lds[0]);
    int t1 = __builtin_amdgcn_readfirstlane(tok_lds[1]);
    int t2 = __builtin_amdgcn_readfirstlane(tok_lds[2]);
    int t3 = __builtin_amdgcn_readfirstlane(tok_lds[3]);
    gq0 = *reinterpret_cast<const float4*>(Gd + ((size_t)t0 << 8) + (u << 2));
    gq1 = *reinterpret_cast<const float4*>(Gd + ((size_t)t1 << 8) + (u << 2));
    gq2 = *reinterpret_cast<const float4*>(Gd + ((size_t)t2 << 8) + (u << 2));
    gq3 = *reinterpret_cast<const float4*>(Gd + ((size_t)t3 << 8) + (u << 2));
  }
  int tk_next = tok_lds[4];   // token for step 4, register-carried

  int cur = 0;
  for (int s = 0; s < T_; ++s) {
    // issue next row load first (token already in register, lgkm-clean)
    int tokn = __builtin_amdgcn_readfirstlane(tk_next);
    float4 gq4 = *reinterpret_cast<const float4*>(Gd + ((size_t)tokn << 8) + (u << 2));
    tk_next = tok_lds[s + 5];   // ds_read completes under this step's barrier drain

    const float* hq = hls[cur] + (kq << 4);
    float4 h0 = *reinterpret_cast<const float4*>(hq + 0);
    float4 h1 = *reinterpret_cast<const float4*>(hq + 4);
    float4 h2 = *reinterpret_cast<const float4*>(hq + 8);
    float4 h3 = *reinterpret_cast<const float4*>(hq + 12);
    // per-gate 16-elem dot; first term fmaf(a,b,0) == a*b bit-exact
#define GDOT(res, Wa, Wb, Wc, Wd) float res; { \
    float b0 = Wa.x * h0.x; float b1 = Wa.y * h0.y; float b2 = Wa.z * h0.z; float b3 = Wa.w * h0.w; \
    b0 = fmaf(Wb.x, h1.x, b0); b1 = fmaf(Wb.y, h1.y, b1); b2 = fmaf(Wb.z, h1.z, b2); b3 = fmaf(Wb.w, h1.w, b3); \
    b0 = fmaf(Wc.x, h2.x, b0); b1 = fmaf(Wc.y, h2.y, b1); b2 = fmaf(Wc.z, h2.z, b2); b3 = fmaf(Wc.w, h2.w, b3); \
    b0 = fmaf(Wd.x, h3.x, b0); b1 = fmaf(Wd.y, h3.y, b1); b2 = fmaf(Wd.z, h3.z, b2); b3 = fmaf(Wd.w, h3.w, b3); \
    res = (b0 + b1) + (b2 + b3); }
    GDOT(acc0, W00, W01, W02, W03)
    GDOT(acc1, W10, W11, W12, W13)
    GDOT(acc2, W20, W21, W22, W23)
    GDOT(acc3, W30, W31, W32, W33)
#undef GDOT
    // quad butterfly (DPP, no DS ops): every lane gets full 64-sum per gate
    float t0 = acc0 + qp_xor1(acc0); float f0 = t0 + qp_xor2(t0);
    float t1 = acc1 + qp_xor1(acc1); float f1 = t1 + qp_xor2(t1);
    float t2 = acc2 + qp_xor1(acc2); float f2 = t2 + qp_xor2(t2);
    float t3 = acc3 + qp_xor1(acc3); float f3 = t3 + qp_xor2(t3);
    float xi = f0 + gq0.x;
    float xf = f1 + gq0.y;
    float xg = f2 + gq0.z;
    float xo = f3 + gq0.w;
    // same activation formulas as rounds 4-8 (verified absmax 0.0)
    float si = __builtin_amdgcn_rcpf(1.0f + __builtin_amdgcn_exp2f(xi * (-L2E)));
    float sf = __builtin_amdgcn_rcpf(1.0f + __builtin_amdgcn_exp2f(xf * (-L2E)));
    float tg = fmaf(2.0f, __builtin_amdgcn_rcpf(1.0f + __builtin_amdgcn_exp2f(xg * (-2.0f * L2E))), -1.0f);
    float so = __builtin_amdgcn_rcpf(1.0f + __builtin_amdgcn_exp2f(xo * (-L2E)));
    c = __fadd_rn(__fmul_rn(sf, c), __fmul_rn(si, tg));
    float tc = fmaf(2.0f, __builtin_amdgcn_rcpf(1.0f + __builtin_amdgcn_exp2f(c * (-2.0f * L2E))), -1.0f);
    float hn = __fmul_rn(so, tc);
    if (kq == 0) {
      hls[cur ^ 1][u] = hn;
      *hop = hn;
    }
    hop += hstep;
    // raw barrier: drain LDS only; global prefetch loads stay in flight
    asm volatile("s_waitcnt lgkmcnt(0)\n\ts_barrier" ::: "memory");
    cur ^= 1;
    gq0 = gq1; gq1 = gq2; gq2 = gq3; gq3 = gq4;
  }
}

// ============ K3: emissions = [hf|hb] @ W_out.T + b_out ============
__global__ __launch_bounds__(256) void k3_emit(
    const float* __restrict__ hbuf,
    const float* __restrict__ W_out,
    const float* __restrict__ b_out,
    float* __restrict__ emit)
{
  __shared__ float hl[64][132];
  __shared__ float Wl[17][132];
  int tid = threadIdx.x;
  int p0 = blockIdx.x * 64;  // flat position base (b*T + t), 64 consecutive t
  const float* hf = hbuf;
  const float* hb = hbuf + (size_t)B_ * T_ * H_;
#pragma unroll
  for (int i = 0; i < 4; ++i) {
    int idx = tid + i * 256;       // float4 index among 1024
    int pos = idx >> 4, e4 = idx & 15;
    float4 v = reinterpret_cast<const float4*>(hf + (size_t)p0 * 64)[idx];
    *reinterpret_cast<float4*>(&hl[pos][e4 * 4]) = v;
    float4 v2 = reinterpret_cast<const float4*>(hb + (size_t)p0 * 64)[idx];
    *reinterpret_cast<float4*>(&hl[pos][64 + e4 * 4]) = v2;
  }
  for (int i = tid; i < 17 * 128; i += 256) {
    int k = i >> 7, e = i & 127;
    Wl[k][e] = W_out[i];
  }
  __syncthreads();

  int pos = tid >> 2, ks = tid & 3;
  float acc[5] = {0.f, 0.f, 0.f, 0.f, 0.f};
#pragma unroll
  for (int e4 = 0; e4 < 32; ++e4) {
    float4 x4 = *reinterpret_cast<const float4*>(&hl[pos][e4 * 4]);
#pragma unroll
    for (int kk = 0; kk < 5; ++kk) {
      int k = ks + kk * 4;
      if (k < K_) {
        float4 w4 = *reinterpret_cast<const float4*>(&Wl[k][e4 * 4]);
        acc[kk] = fmaf(x4.x, w4.x, acc[kk]);
        acc[kk] = fmaf(x4.y, w4.y, acc[kk]);
        acc[kk] = fmaf(x4.z, w4.z, acc[kk]);
        acc[kk] = fmaf(x4.w, w4.w, acc[kk]);
      }
    }
  }
#pragma unroll
  for (int kk = 0; kk < 5; ++kk) {
    int k = ks + kk * 4;
    if (k < K_)
      emit[(size_t)(p0 + pos) * K_ + k] = __fadd_rn(acc[kk], b_out[k]);
  }
}

// ============ K4: Viterbi forward. 1 wave per b; lane = (half ic, tag j) ============
#define AMAX(vA, iA, vB, iB) { bool tk_ = (vB) > (vA); if (tk_) { vA = (vB); iA = (iB); } }

__global__ __launch_bounds__(64) void k4_viterbi(
    const float* __restrict__ emit,
    const float* __restrict__ trans,
    const float* __restrict__ start_trans,
    const float* __restrict__ end_trans,
    u8* __restrict__ bp,
    int* __restrict__ last,
    float* __restrict__ out)
{
  int b = blockIdx.x;
  int l = threadIdx.x;
  int ic = l >> 5;
  int hbase = l & 32;
  int j = l & 31;
  int jc = (j < K_) ? j : 0;
  int i0 = ic ? 9 : 0;
  int cnt = ic ? 8 : 9;
  // named scalars (no array -> no SROA hazard)
  float tr0 = trans[(i0 + 0) * K_ + jc];
  float tr1 = trans[(i0 + 1) * K_ + jc];
  float tr2 = trans[(i0 + 2) * K_ + jc];
  float tr3 = trans[(i0 + 3) * K_ + jc];
  float tr4 = trans[(i0 + 4) * K_ + jc];
  float tr5 = trans[(i0 + 5) * K_ + jc];
  float tr6 = trans[(i0 + 6) * K_ + jc];
  float tr7 = trans[(i0 + 7) * K_ + jc];
  float tr8 = (cnt > 8) ? trans[(i0 + 8) * K_ + jc] : -__builtin_inff();
  asm volatile("" : "+v"(tr0), "+v"(tr1), "+v"(tr2), "+v"(tr3), "+v"(tr4),
                    "+v"(tr5), "+v"(tr6), "+v"(tr7), "+v"(tr8));
  const float* eb = emit + (size_t)b * T_ * K_;
  float endt = end_trans[jc];
  float s = __fadd_rn(start_trans[jc], eb[jc]);
  u8* bpb = bp + (size_t)b * T_ * 32;
  // 4-deep emission prefetch ring
  float er0 = eb[1 * K_ + jc];
  float er1 = eb[2 * K_ + jc];
  float er2 = eb[3 * K_ + jc];
  float er3 = eb[4 * K_ + jc];

  for (int t = 1; t < T_; ++t) {
    float ej = er0;
    er0 = er1; er1 = er2; er2 = er3;
    if (t + 4 < T_) er3 = eb[(size_t)(t + 4) * K_ + jc];
    float p0 = __shfl(s, hbase + i0 + 0, 64);
    float p1 = __shfl(s, hbase + i0 + 1, 64);
    float p2 = __shfl(s, hbase + i0 + 2, 64);
    float p3 = __shfl(s, hbase + i0 + 3, 64);
    float p4 = __shfl(s, hbase + i0 + 4, 64);
    float p5 = __shfl(s, hbase + i0 + 5, 64);
    float p6 = __shfl(s, hbase + i0 + 6, 64);
    float p7 = __shfl(s, hbase + i0 + 7, 64);
    float p8 = __shfl(s, hbase + i0 + 8, 64);
    // np rounding order: cand = (score_i + trans_ij) + emit_j
    float c0 = __fadd_rn(__fadd_rn(p0, tr0), ej);
    float c1 = __fadd_rn(__fadd_rn(p1, tr1), ej);
    float c2 = __fadd_rn(__fadd_rn(p2, tr2), ej);
    float c3 = __fadd_rn(__fadd_rn(p3, tr3), ej);
    float c4 = __fadd_rn(__fadd_rn(p4, tr4), ej);
    float c5 = __fadd_rn(__fadd_rn(p5, tr5), ej);
    float c6 = __fadd_rn(__fadd_rn(p6, tr6), ej);
    float c7 = __fadd_rn(__fadd_rn(p7, tr7), ej);
    float c8 = __fadd_rn(__fadd_rn(p8, tr8), ej);
    // tree argmax; strict > with left-priority == np first-index tie rule
    float v01 = c0; int x01 = i0;     AMAX(v01, x01, c1, i0 + 1);
    float v23 = c2; int x23 = i0 + 2; AMAX(v23, x23, c3, i0 + 3);
    float v45 = c4; int x45 = i0 + 4; AMAX(v45, x45, c5, i0 + 5);
    float v67 = c6; int x67 = i0 + 6; AMAX(v67, x67, c7, i0 + 7);
    AMAX(v01, x01, v23, x23);
    AMAX(v45, x45, v67, x67);
    AMAX(v01, x01, v45, x45);
    AMAX(v01, x01, c8, i0 + 8);
    float m = v01; int idx = x01;
    float m2 = __shfl_xor(m, 32, 64);
    int idx2 = __shfl_xor(idx, 32, 64);
    bool take = (m2 > m) || ((m2 == m) && (idx2 < idx));
    if (take) { m = m2; idx = idx2; }
    s = m;
    if (ic == 0 && j < K_) bpb[(size_t)(t - 1) * 32 + j] = (u8)idx;
  }
  float fin = __fadd_rn(s, endt);
  float bm = __shfl(fin, hbase, 64);
  int bi = 0;
#pragma unroll
  for (int jj = 1; jj < K_; ++jj) {
    float v = __shfl(fin, hbase + jj, 64);
    if (v > bm) { bm = v; bi = jj; }
  }
  if (l == 0) {
    out[b] = bm;
    last[b] = bi;
    out[256 + (size_t)b * T_ + (T_ - 1)] = (float)bi;
  }
}

// ============ K5: backtrace — 8-deep double-buffered prefetch ============
__global__ __launch_bounds__(64) void k5_backtrace(
    const u8* __restrict__ bp,
    const int* __restrict__ last,
    float* __restrict__ out)
{
  int b = blockIdx.x * 64 + threadIdx.x;
  const u8* base = bp + (size_t)b * T_ * 32;
  int tag = last[b];
  float* ob = out + 256 + (size_t)b * T_;
  uint4 A0[8], A1[8];
  u32 B0[8], B1[8];
#pragma unroll
  for (int q = 0; q < 8; ++q) {
    const u8* p = base + (size_t)(510 - q) * 32;
    A0[q] = *reinterpret_cast<const uint4*>(p);
    B0[q] = *reinterpret_cast<const u32*>(p + 16);
  }
  int t0 = 510;
  for (int pair = 0; pair < 32; ++pair) {
#pragma unroll
    for (int q = 0; q < 8; ++q) {
      int tn = t0 - 8 - q;
      if (tn >= 0) {
        const u8* p = base + (size_t)tn * 32;
        A1[q] = *reinterpret_cast<const uint4*>(p);
        B1[q] = *reinterpret_cast<const u32*>(p + 16);
      }
    }
#pragma unroll
    for (int q = 0; q < 8; ++q) {
      int t = t0 - q;
      if (t >= 0) {
        uint4 Av = A0[q]; u32 Bw = B0[q];
        u32 dw = (tag < 8) ? ((tag < 4) ? Av.x : Av.y) : ((tag < 12) ? Av.z : Av.w);
        dw = (tag < 16) ? dw : Bw;
        tag = (int)((dw >> ((tag & 3) * 8)) & 0xffu);
        ob[t] = (float)tag;
      }
    }
#pragma unroll
    for (int q = 0; q < 8; ++q) {
      int tn = t0 - 16 - q;
      if (tn >= 0) {
        const u8* p = base + (size_t)tn * 32;
        A0[q] = *reinterpret_cast<const uint4*>(p);
        B0[q] = *reinterpret_cast<const u32*>(p + 16);
      }
    }
#pragma unroll
    for (int q = 0; q < 8; ++q) {
      int t = t0 - 8 - q;
      if (t >= 0) {
        uint4 Av = A1[q]; u32 Bw = B1[q];
        u32 dw = (tag < 8) ? ((tag < 4) ? Av.x : Av.y) : ((tag < 12) ? Av.z : Av.w);
        dw = (tag < 16) ? dw : Bw;
        tag = (int)((dw >> ((tag & 3) * 8)) & 0xffu);
        ob[t] = (float)tag;
      }
    }
    t0 -= 16;
  }
}

extern "C" void kernel_launch(void* const* d_in, const int* in_sizes, int n_in,
                              void* d_out, int out_size, void* d_ws, size_t ws_size,
                              hipStream_t stream) {
  const int*   data  = (const int*)d_in[0];
  const float* emb   = (const float*)d_in[2];
  const float* Wih_f = (const float*)d_in[3];
  const float* Whh_f = (const float*)d_in[4];
  const float* bih_f = (const float*)d_in[5];
  const float* bhh_f = (const float*)d_in[6];
  const float* Wih_b = (const float*)d_in[7];
  const float* Whh_b = (const float*)d_in[8];
  const float* bih_b = (const float*)d_in[9];
  const float* bhh_b = (const float*)d_in[10];
  const float* W_out = (const float*)d_in[11];
  const float* b_out = (const float*)d_in[12];
  const float* trans = (const float*)d_in[13];
  const float* start_trans = (const float*)d_in[14];
  const float* end_trans   = (const float*)d_in[15];

  char* ws = (char*)d_ws;
  float* G    = (float*)(ws + WS_G);
  float* hbuf = (float*)(ws + WS_H);
  float* emit = (float*)(ws + WS_EMIT);
  u8*    bp   = (u8*)(ws + WS_BP);
  int*   lastp = (int*)(ws + WS_LAST);
  float* out = (float*)d_out;

  k1_build_G<<<dim3(250, 2), 256, 0, stream>>>(emb, Wih_f, bih_f, bhh_f,
                                               Wih_b, bih_b, bhh_b, G);
  k2_lstm<<<512, 256, 0, stream>>>(data, G, Whh_f, Whh_b, hbuf);
  k3_emit<<<2048, 256, 0, stream>>>(hbuf, W_out, b_out, emit);
  k4_viterbi<<<256, 64, 0, stream>>>(emit, trans, start_trans, end_trans,
                                     bp, lastp, out);
  k5_backtrace<<<4, 64, 0, stream>>>(bp, lastp, out);
}